// Round 11
// baseline (432.269 us; speedup 1.0000x reference)
//
#include <hip/hip_runtime.h>

#define HIDDEN 256
#define NGRAPH 1024
#define EPS 1e-6f
#define STAGE_ROWS 156    // slab head staged in LDS (159.8 KB of the 160 KiB/CU)
#define CACHE_SWEEPS 12   // last ~721 rows per slab cacheable (~185 MB aggregate < 256 MB L3)

typedef float f32x4 __attribute__((ext_vector_type(4)));

__device__ __forceinline__ float ssum(const f32x4 v) {
    return v.x * v.x + v.y * v.y + v.z * v.z + v.w * v.w;
}

// One block per graph (batch sorted => graph g owns contiguous rows [start,end)).
//
// Explicit cache-policy windowing: phase A loads are
//   rows 0..155          : NT load -> LDS stage (never needed from memory again)
//   middle (~100 rows)   : NT load (conceded phase-B misses; kept OUT of L3)
//   last 12 sweeps       : cacheable — the only L3-allocating stream.
//                          ~721 rows x 1 KB x 256 resident blocks ~= 185 MB < L3.
// Phase B (reverse sweep order): tail from L3 (hits), middle via NT (HBM),
// head from LDS. All output via NT stores (write stream must not evict x).
//
// 159.8 KB static LDS forces 1 block/CU (256 resident blocks, 4 rounds).
__global__ __launch_bounds__(512) void k_fused(
    const float* __restrict__ x, const int* __restrict__ batch,
    const float* __restrict__ w, float* __restrict__ out, int n_nodes) {

    __shared__ float smem[STAGE_ROWS * HIDDEN + 8];   // stage + reduce scratch

    const int g    = (int)blockIdx.x;
    const int tid  = (int)threadIdx.x;
    const int lane = tid & 63;
    const int wid  = tid >> 6;      // 0..7

    // Binary-search graph bounds (wave-uniform broadcast loads, ~40 total).
    int lo = 0, hi = n_nodes;
    while (lo < hi) { int m = (lo + hi) >> 1; if (batch[m] < g) lo = m + 1; else hi = m; }
    const int start = lo;
    int lo2 = start, hi2 = n_nodes;
    while (lo2 < hi2) { int m = (lo2 + hi2) >> 1; if (batch[m] < g + 1) lo2 = m + 1; else hi2 = m; }
    const int count = lo2 - start;
    if (count <= 0) return;         // block-uniform: safe w.r.t. __syncthreads below

    const int nsweep     = (count + 63) >> 6;   // 8 waves x 8 rows per sweep
    const int cache_from = (nsweep > CACHE_SWEEPS) ? (nsweep - CACHE_SWEEPS) : 0;

    // ---- Phase A: sum of squares, explicit per-region cache policy ----
    float acc = 0.0f;
    for (int s = 0; s < nsweep; ++s) {
        const int base = (s << 6) + (wid << 3);
        if (base + 8 <= count) {
            f32x4 v[8];
            if (base + 8 <= STAGE_ROWS) {
                // Head: NT load + LDS stage.
                #pragma unroll
                for (int k = 0; k < 8; ++k)
                    v[k] = __builtin_nontemporal_load(reinterpret_cast<const f32x4*>(
                        x + (size_t)(start + base + k) * HIDDEN + (size_t)lane * 4));
                #pragma unroll
                for (int k = 0; k < 8; ++k)
                    *reinterpret_cast<f32x4*>(&smem[(base + k) * HIDDEN + lane * 4]) = v[k];
            } else if (s < cache_from) {
                // Middle: NT load, no L3 allocation.
                #pragma unroll
                for (int k = 0; k < 8; ++k)
                    v[k] = __builtin_nontemporal_load(reinterpret_cast<const f32x4*>(
                        x + (size_t)(start + base + k) * HIDDEN + (size_t)lane * 4));
            } else {
                // Tail window: cacheable (the only L3-allocating stream).
                #pragma unroll
                for (int k = 0; k < 8; ++k)
                    v[k] = *reinterpret_cast<const f32x4*>(
                        x + (size_t)(start + base + k) * HIDDEN + (size_t)lane * 4);
            }
            #pragma unroll
            for (int k = 0; k < 8; ++k) acc += ssum(v[k]);
        } else {
            for (int r = base; r < count; ++r)
                acc += ssum(*reinterpret_cast<const f32x4*>(
                    x + (size_t)(start + r) * HIDDEN + (size_t)lane * 4));
        }
    }
    #pragma unroll
    for (int off = 32; off > 0; off >>= 1)
        acc += __shfl_xor(acc, off);
    if (lane == 0) smem[STAGE_ROWS * HIDDEN + wid] = acc;
    __syncthreads();

    float total = 0.0f;
    #pragma unroll
    for (int k = 0; k < 8; ++k) total += smem[STAGE_ROWS * HIDDEN + k];
    const float mean = total / ((float)count * (float)HIDDEN);
    const float rr   = 1.0f / sqrtf(mean + EPS);

    // ---- Phase B: normalize; reverse sweep order; LDS head + NT loads; NT stores ----
    const f32x4 wv = *reinterpret_cast<const f32x4*>(w + (size_t)lane * 4);
    for (int s = nsweep - 1; s >= 0; --s) {
        const int base = (s << 6) + (wid << 3);
        if (base + 8 <= count) {
            f32x4 v[8];
            if (base + 8 <= STAGE_ROWS) {   // staged in phase A by THIS wave
                #pragma unroll
                for (int k = 0; k < 8; ++k)
                    v[k] = *reinterpret_cast<const f32x4*>(
                        &smem[(base + k) * HIDDEN + lane * 4]);
            } else {
                #pragma unroll
                for (int k = 0; k < 8; ++k)
                    v[k] = __builtin_nontemporal_load(reinterpret_cast<const f32x4*>(
                        x + (size_t)(start + base + k) * HIDDEN + (size_t)lane * 4));
            }
            #pragma unroll
            for (int k = 0; k < 8; ++k) {
                f32x4 o = { v[k].x * wv.x * rr, v[k].y * wv.y * rr,
                            v[k].z * wv.z * rr, v[k].w * wv.w * rr };
                __builtin_nontemporal_store(o, reinterpret_cast<f32x4*>(
                    out + (size_t)(start + base + k) * HIDDEN + (size_t)lane * 4));
            }
        } else {
            for (int r = base; r < count; ++r) {
                const f32x4 v = __builtin_nontemporal_load(reinterpret_cast<const f32x4*>(
                    x + (size_t)(start + r) * HIDDEN + (size_t)lane * 4));
                f32x4 o = { v.x * wv.x * rr, v.y * wv.y * rr,
                            v.z * wv.z * rr, v.w * wv.w * rr };
                __builtin_nontemporal_store(o, reinterpret_cast<f32x4*>(
                    out + (size_t)(start + r) * HIDDEN + (size_t)lane * 4));
            }
        }
    }
}

extern "C" void kernel_launch(void* const* d_in, const int* in_sizes, int n_in,
                              void* d_out, int out_size, void* d_ws, size_t ws_size,
                              hipStream_t stream) {
    const float* x     = (const float*)d_in[0];
    const int*   batch = (const int*)d_in[1];
    const float* w     = (const float*)d_in[2];
    float*       out   = (float*)d_out;
    const int n_nodes  = in_sizes[1];

    // One block per graph; 512 threads = 8 waves; ~160 KB LDS -> 1 block/CU.
    k_fused<<<NGRAPH, 512, 0, stream>>>(x, batch, w, out, n_nodes);
}

// Round 12
// 432.169 us; speedup vs baseline: 1.0002x; 1.0002x over previous
//
#include <hip/hip_runtime.h>

#define HIDDEN 256
#define NGRAPH 1024
#define EPS 1e-6f
#define STAGE_ROWS 156    // slab head staged in LDS (~156 KB of the 160 KiB/CU)
#define CACHE_ROWS 704    // last ~704 rows per slab cacheable (~180 MB aggregate < 256 MB L3)

typedef float f32x4 __attribute__((ext_vector_type(4)));

__device__ __forceinline__ float ssum(const f32x4 v) {
    return v.x * v.x + v.y * v.y + v.z * v.z + v.w * v.w;
}

// One block per graph (batch sorted => graph g owns contiguous rows [start,end)).
//
// r12 change: 1024-thread blocks (16 waves = 4 waves/SIMD, up from 2) to test
// the occupancy-limited-streaming theory — r10/r11 showed dur does not respond
// to modeled L3 miss traffic, so the plateau is likely issue-rate, not BW.
// LDS (156 KB) still forces 1 block/CU: resident footprint model unchanged.
//
// Cache policy per phase-A load:
//   rows 0..155             : NT load -> LDS stage (never needed from memory again)
//   middle                  : NT load (conceded phase-B misses; kept OUT of L3)
//   last 704 rows           : cacheable — the only L3-allocating stream
//                             (704 KB x 256 resident blocks ~= 180 MB < L3).
// Phase B (reverse sweep order): tail from L3, middle via NT, head from LDS;
// all output via NT stores (write stream must not evict x).
__global__ __launch_bounds__(1024) void k_fused(
    const float* __restrict__ x, const int* __restrict__ batch,
    const float* __restrict__ w, float* __restrict__ out, int n_nodes) {

    __shared__ float smem[STAGE_ROWS * HIDDEN + 16];   // stage + reduce scratch

    const int g    = (int)blockIdx.x;
    const int tid  = (int)threadIdx.x;
    const int lane = tid & 63;
    const int wid  = tid >> 6;      // 0..15

    // Binary-search graph bounds (wave-uniform broadcast loads, ~40 total).
    int lo = 0, hi = n_nodes;
    while (lo < hi) { int m = (lo + hi) >> 1; if (batch[m] < g) lo = m + 1; else hi = m; }
    const int start = lo;
    int lo2 = start, hi2 = n_nodes;
    while (lo2 < hi2) { int m = (lo2 + hi2) >> 1; if (batch[m] < g + 1) lo2 = m + 1; else hi2 = m; }
    const int count = lo2 - start;
    if (count <= 0) return;         // block-uniform: safe w.r.t. __syncthreads below

    const int nsweep = (count + 127) >> 7;                       // 16 waves x 8 rows
    const int cache_from_row = (count > CACHE_ROWS) ? (count - CACHE_ROWS) : 0;

    // ---- Phase A: sum of squares, explicit per-region cache policy ----
    float acc = 0.0f;
    for (int s = 0; s < nsweep; ++s) {
        const int base = (s << 7) + (wid << 3);
        if (base + 8 <= count) {
            f32x4 v[8];
            if (base + 8 <= STAGE_ROWS) {
                // Head: NT load + LDS stage.
                #pragma unroll
                for (int k = 0; k < 8; ++k)
                    v[k] = __builtin_nontemporal_load(reinterpret_cast<const f32x4*>(
                        x + (size_t)(start + base + k) * HIDDEN + (size_t)lane * 4));
                #pragma unroll
                for (int k = 0; k < 8; ++k)
                    *reinterpret_cast<f32x4*>(&smem[(base + k) * HIDDEN + lane * 4]) = v[k];
            } else if (base >= cache_from_row) {
                // Tail window: cacheable (the only L3-allocating stream).
                #pragma unroll
                for (int k = 0; k < 8; ++k)
                    v[k] = *reinterpret_cast<const f32x4*>(
                        x + (size_t)(start + base + k) * HIDDEN + (size_t)lane * 4);
            } else {
                // Middle: NT load, no L3 allocation.
                #pragma unroll
                for (int k = 0; k < 8; ++k)
                    v[k] = __builtin_nontemporal_load(reinterpret_cast<const f32x4*>(
                        x + (size_t)(start + base + k) * HIDDEN + (size_t)lane * 4));
            }
            #pragma unroll
            for (int k = 0; k < 8; ++k) acc += ssum(v[k]);
        } else {
            for (int r = base; r < count; ++r)
                acc += ssum(*reinterpret_cast<const f32x4*>(
                    x + (size_t)(start + r) * HIDDEN + (size_t)lane * 4));
        }
    }
    #pragma unroll
    for (int off = 32; off > 0; off >>= 1)
        acc += __shfl_xor(acc, off);
    if (lane == 0) smem[STAGE_ROWS * HIDDEN + wid] = acc;
    __syncthreads();

    float total = 0.0f;
    #pragma unroll
    for (int k = 0; k < 16; ++k) total += smem[STAGE_ROWS * HIDDEN + k];
    const float mean = total / ((float)count * (float)HIDDEN);
    const float rr   = 1.0f / sqrtf(mean + EPS);

    // ---- Phase B: normalize; reverse sweep order; LDS head + NT loads; NT stores ----
    const f32x4 wv = *reinterpret_cast<const f32x4*>(w + (size_t)lane * 4);
    for (int s = nsweep - 1; s >= 0; --s) {
        const int base = (s << 7) + (wid << 3);
        if (base + 8 <= count) {
            f32x4 v[8];
            if (base + 8 <= STAGE_ROWS) {   // staged in phase A by THIS wave
                #pragma unroll
                for (int k = 0; k < 8; ++k)
                    v[k] = *reinterpret_cast<const f32x4*>(
                        &smem[(base + k) * HIDDEN + lane * 4]);
            } else {
                #pragma unroll
                for (int k = 0; k < 8; ++k)
                    v[k] = __builtin_nontemporal_load(reinterpret_cast<const f32x4*>(
                        x + (size_t)(start + base + k) * HIDDEN + (size_t)lane * 4));
            }
            #pragma unroll
            for (int k = 0; k < 8; ++k) {
                f32x4 o = { v[k].x * wv.x * rr, v[k].y * wv.y * rr,
                            v[k].z * wv.z * rr, v[k].w * wv.w * rr };
                __builtin_nontemporal_store(o, reinterpret_cast<f32x4*>(
                    out + (size_t)(start + base + k) * HIDDEN + (size_t)lane * 4));
            }
        } else {
            for (int r = base; r < count; ++r) {
                const f32x4 v = __builtin_nontemporal_load(reinterpret_cast<const f32x4*>(
                    x + (size_t)(start + r) * HIDDEN + (size_t)lane * 4));
                f32x4 o = { v.x * wv.x * rr, v.y * wv.y * rr,
                            v.z * wv.z * rr, v.w * wv.w * rr };
                __builtin_nontemporal_store(o, reinterpret_cast<f32x4*>(
                    out + (size_t)(start + r) * HIDDEN + (size_t)lane * 4));
            }
        }
    }
}

extern "C" void kernel_launch(void* const* d_in, const int* in_sizes, int n_in,
                              void* d_out, int out_size, void* d_ws, size_t ws_size,
                              hipStream_t stream) {
    const float* x     = (const float*)d_in[0];
    const int*   batch = (const int*)d_in[1];
    const float* w     = (const float*)d_in[2];
    float*       out   = (float*)d_out;
    const int n_nodes  = in_sizes[1];

    // One block per graph; 1024 threads = 16 waves; 156 KB LDS -> 1 block/CU.
    k_fused<<<NGRAPH, 1024, 0, stream>>>(x, batch, w, out, n_nodes);
}